// Round 8
// baseline (253.787 us; speedup 1.0000x reference)
//
#include <hip/hip_runtime.h>

typedef unsigned int u32;
typedef unsigned short u16;
typedef unsigned long long u64;
typedef float f32x4 __attribute__((ext_vector_type(4)));
typedef float f32x2 __attribute__((ext_vector_type(2)));
typedef u32 u32x4 __attribute__((ext_vector_type(4)));
typedef u32 u32x2 __attribute__((ext_vector_type(2)));

#define DEVINL static __device__ __forceinline__
#define LOG2E 1.44269504088896340736f
#define QSCALE 0.18033688011112042f /* 0.125 * LOG2E */

DEVINL u16 f2bf(float f) {
  u32 u = __builtin_bit_cast(u32, f);
  u32 r = u + 0x7FFFu + ((u >> 16) & 1u);
  return (u16)(r >> 16);
}

DEVINL u32 cvtpk(float lo, float hi) {
  u32 r;
  asm("v_cvt_pk_bf16_f32 %0, %1, %2" : "=v"(r) : "v"(lo), "v"(hi));
  return r;
}
DEVINL float exp2v(float x) {
  float r;
  asm("v_exp_f32 %0, %1" : "=v"(r) : "v"(x));
  return r;
}
DEVINL void mfma_b16(f32x4& c, u32x4 a, u32x4 b) {
  asm volatile("v_mfma_f32_16x16x32_bf16 %0, %1, %2, %0" : "+v"(c) : "v"(a), "v"(b));
}
DEVINL void mfma_fence() { asm volatile("s_nop 7\n\ts_nop 7"); }

DEVINL int mbcnt64(u64 m) {
  return __builtin_amdgcn_mbcnt_hi((u32)(m >> 32), __builtin_amdgcn_mbcnt_lo((u32)m, 0));
}
DEVINL u64 shfl_xor64(u64 v, int m) {
  u32 lo = (u32)v, hi = (u32)(v >> 32);
  lo = __shfl_xor(lo, m, 64);
  hi = __shfl_xor(hi, m, 64);
  return ((u64)hi << 32) | lo;
}

// ---------------------------------------------------------------------------
// prep: x -> bf16; tiled transpose of Wq/Wk/Wv -> WqkvT [1536][256] bf16 and
// Wo -> WoT [512][512] bf16; concat qkv bias. Grid = 1024 + 96 + 64 + 1.
// ---------------------------------------------------------------------------
__global__ __launch_bounds__(256) void prep_kernel(
    const float* __restrict__ x, const float* __restrict__ Wq, const float* __restrict__ Wk,
    const float* __restrict__ Wv, const float* __restrict__ Wo, const float* __restrict__ bq,
    const float* __restrict__ bk, const float* __restrict__ bv, u16* __restrict__ xb,
    u16* __restrict__ WqkvT, u16* __restrict__ WoT, float* __restrict__ biasQKV) {
  __shared__ float T[64][65];
  const int blk = blockIdx.x, tid = threadIdx.x;
  if (blk < 1024) {  // x convert: 2,097,152 elems, 8/thread
    int i0 = (blk * 256 + tid) * 8;
    f32x4 v0 = *(const f32x4*)(x + i0);
    f32x4 v1 = *(const f32x4*)(x + i0 + 4);
    u32x4 pk;
    pk[0] = (u32)f2bf(v0[0]) | ((u32)f2bf(v0[1]) << 16);
    pk[1] = (u32)f2bf(v0[2]) | ((u32)f2bf(v0[3]) << 16);
    pk[2] = (u32)f2bf(v1[0]) | ((u32)f2bf(v1[1]) << 16);
    pk[3] = (u32)f2bf(v1[2]) | ((u32)f2bf(v1[3]) << 16);
    *(u32x4*)(xb + i0) = pk;
    return;
  }
  if (blk < 1024 + 96 + 64) {  // weight transposes, 64x64 f32 tiles
    int t = blk - 1024;
    const float* W;
    u16* dst;
    int k0, n0, outld, outrow0;
    if (t < 96) {
      int sel = t >> 5, tt = t & 31;
      W = sel == 0 ? Wq : (sel == 1 ? Wk : Wv);
      k0 = (tt >> 3) * 64;
      n0 = (tt & 7) * 64;
      dst = WqkvT;
      outld = 256;
      outrow0 = sel * 512 + n0;
    } else {
      int tt = t - 96;
      W = Wo;
      k0 = (tt >> 3) * 64;
      n0 = (tt & 7) * 64;
      dst = WoT;
      outld = 512;
      outrow0 = n0;
    }
    const int r = tid >> 2, q = tid & 3;
#pragma unroll
    for (int i = 0; i < 4; i++) {
      f32x4 vv = *(const f32x4*)(W + (size_t)(k0 + r) * 512 + n0 + q * 16 + i * 4);
      T[r][q * 16 + i * 4 + 0] = vv[0];
      T[r][q * 16 + i * 4 + 1] = vv[1];
      T[r][q * 16 + i * 4 + 2] = vv[2];
      T[r][q * 16 + i * 4 + 3] = vv[3];
    }
    __syncthreads();
    u16 tmpv[16];
#pragma unroll
    for (int e = 0; e < 16; e++) tmpv[e] = f2bf(T[q * 16 + e][r]);
    u32x4 w0, w1;
#pragma unroll
    for (int j = 0; j < 4; j++) {
      w0[j] = (u32)tmpv[2 * j] | ((u32)tmpv[2 * j + 1] << 16);
      w1[j] = (u32)tmpv[8 + 2 * j] | ((u32)tmpv[9 + 2 * j] << 16);
    }
    u16* dp = dst + (size_t)(outrow0 + r) * outld + k0 + q * 16;
    *(u32x4*)dp = w0;
    *(u32x4*)(dp + 8) = w1;
    return;
  }
  for (int i = tid; i < 1536; i += 256)
    biasQKV[i] = i < 512 ? bq[i] : (i < 1024 ? bk[i - 512] : bv[i - 1024]);
}

// ---------------------------------------------------------------------------
// topk: one wave per row. Threshold-select + ballot compaction + 64-lane
// bitonic sort -> exact jax top-32 with tie-break. Output: 32 packed entries
// (idx<<16 | bf16(tau*w*LOG2E)) sorted by (g-bucket=(idx>>2)&3, idx), packed
// bucket starts, and per-bucket counts of entries with idx<1024 (for splitKV).
// ---------------------------------------------------------------------------
__global__ __launch_bounds__(256) void topk_kernel(const float* __restrict__ sim,
                                                   const float* __restrict__ tau_raw,
                                                   u32* __restrict__ tpw,
                                                   u32* __restrict__ tstarts,
                                                   u32* __restrict__ tlo) {
  __shared__ u32 keyA[4][64];
  __shared__ u32 idxA[4][64];
  const int tid = threadIdx.x, lane = tid & 63, w = tid >> 6;
  const int row = blockIdx.x * 4 + w;
  const int b = row >> 11, n = row & 2047;
  const float* src = sim + ((size_t)b * 2048 + n) * 2048;

  // keys: monotonic u32 encoding of clamped value; self -> 0 (never selected)
  u32 keys[32];
#pragma unroll
  for (int q = 0; q < 8; q++) {
    f32x4 v = *(const f32x4*)(src + q * 256 + lane * 4);
#pragma unroll
    for (int j = 0; j < 4; j++) {
      int m = (q << 8) + lane * 4 + j;
      float xv = fmaxf(v[j], 0.f);
      keys[q * 4 + j] = (m == n) ? 0u : (__builtin_bit_cast(u32, xv) + 1u);
    }
  }

  // find threshold P with 32 <= #{key >= P} <= 64
  u32 Plo = 1u;
  u32 Phi = 0x7F000000u;
  u32 P = 0x3F7C0001u;
  int c = 0;
  for (int it = 0; it < 40; ++it) {
    int lc = 0;
#pragma unroll
    for (int e = 0; e < 32; e++) lc += (keys[e] >= P) ? 1 : 0;
#pragma unroll
    for (int off = 1; off < 64; off <<= 1) lc += __shfl_xor(lc, off, 64);
    c = lc;
    if (c >= 32 && c <= 64) break;
    if (c < 32) Phi = P; else Plo = P;
    if (Phi - Plo <= 1) break;
    long long Pn;
    if (P >= 0x3F000000u && P <= 0x3F800000u) {
      Pn = (long long)P + (long long)(c - 48) * 4098;
    } else {
      Pn = (long long)Plo + (long long)((Phi - Plo) >> 1);
    }
    if (Pn <= (long long)Plo || Pn >= (long long)Phi)
      Pn = (long long)Plo + (long long)((Phi - Plo) >> 1);
    P = (u32)Pn;
  }

  // ballot-compact candidates (key >= P) into per-wave LDS
  u32* kws = keyA[w];
  u32* iws = idxA[w];
  int base = 0;
#pragma unroll
  for (int e = 0; e < 32; e++) {
    bool pred = keys[e] >= P;
    u64 mk = __ballot(pred);
    if (pred) {
      int slot = base + mbcnt64(mk);
      if (slot < 64) {
        kws[slot] = keys[e];
        iws[slot] = (u32)((e >> 2) * 256 + lane * 4 + (e & 3));
      }
    }
    base += __popcll(mk);
  }
  for (int s = base + lane; s < 64; s += 64) {
    kws[s] = 0u;
    iws[s] = 2047u;
  }

  // 64-lane bitonic, descending by (key, then ascending idx)
  u64 K = ((u64)kws[lane] << 11) | (u64)(2047u - iws[lane]);
#pragma unroll
  for (int k = 2; k <= 64; k <<= 1) {
#pragma unroll
    for (int j = k >> 1; j >= 1; j >>= 1) {
      u64 o = shfl_xor64(K, j);
      bool keepmax = (((lane & k) == 0) == ((lane & j) == 0));
      u64 mx = K > o ? K : o;
      u64 mn = K > o ? o : K;
      K = keepmax ? mx : mn;
    }
  }

  // lanes 0..31 hold the top-32
  u32 key = (u32)(K >> 11);
  int myidx = 2047 - (int)(K & 0x7FFu);
  float myval = __builtin_bit_cast(float, key - 1u);
  float sv = (lane < 32) ? myval : 0.f;
#pragma unroll
  for (int off = 1; off < 64; off <<= 1) sv += __shfl_xor(sv, off, 64);
  float tau = log1pf(__expf(tau_raw[0]));
  float wvv = tau * myval / fmaxf(sv, 1e-8f) * LOG2E;

  int bucket = (myidx >> 2) & 3;
  u64 bm0 = __ballot(lane < 32 && bucket == 0);
  u64 bm1 = __ballot(lane < 32 && bucket == 1);
  u64 bm2 = __ballot(lane < 32 && bucket == 2);
  int c0 = __popcll(bm0), c1 = __popcll(bm1), c2 = __popcll(bm2);
  // per-bucket counts of entries with idx < 1024 (split-KV jump table)
  bool lo = myidx < 1024;
  u64 l0 = __ballot(lane < 32 && bucket == 0 && lo);
  u64 l1 = __ballot(lane < 32 && bucket == 1 && lo);
  u64 l2 = __ballot(lane < 32 && bucket == 2 && lo);
  u64 l3 = __ballot(lane < 32 && bucket == 3 && lo);
  int key2 = (bucket << 11) | myidx;
  int rank = 0;
  for (int j2 = 0; j2 < 32; j2++) {
    int ok = __shfl(key2, j2, 64);
    rank += (ok < key2) ? 1 : 0;
  }
  if (lane < 32) tpw[(size_t)row * 32 + rank] = ((u32)myidx << 16) | (u32)f2bf(wvv);
  if (lane == 0) {
    tstarts[row] = ((u32)c0 << 8) | ((u32)(c0 + c1) << 16) | ((u32)(c0 + c1 + c2) << 24);
    tlo[row] = (u32)__popcll(l0) | ((u32)__popcll(l1) << 8) | ((u32)__popcll(l2) << 16) |
               ((u32)__popcll(l3) << 24);
  }
}

// ---------------------------------------------------------------------------
// NT GEMM: A [M][K] bf16, Bt [N][K] bf16, 128x128 tile, BK=32, 4 waves.
// MODE 0: scatter bf16 to Q/K/V head-split buffers (Q pre-scaled by QSCALE).
// MODE 1: f32 out [M][N].
// ---------------------------------------------------------------------------
template <int MODE>
__global__ __launch_bounds__(256) void gemm_nt(const u16* __restrict__ A,
                                               const u16* __restrict__ Bt,
                                               const float* __restrict__ bias,
                                               u16* __restrict__ outQ, u16* __restrict__ outK,
                                               u16* __restrict__ outV, float* __restrict__ outF,
                                               int M, int N, int K) {
  __shared__ __align__(16) u16 As[128 * 32];
  __shared__ __align__(16) u16 Bs[128 * 32];

  const int tid = threadIdx.x;
  const int lane = tid & 63;
  const int w = tid >> 6;
  const int g = lane >> 4, c = lane & 15;
  const int wr = (w >> 1) * 64, wc = (w & 1) * 64;
  const int m0 = blockIdx.y * 128, n0 = blockIdx.x * 128;

  f32x4 acc[4][4];
#pragma unroll
  for (int i = 0; i < 4; i++)
#pragma unroll
    for (int j = 0; j < 4; j++) acc[i][j] = f32x4{0.f, 0.f, 0.f, 0.f};

  const int srow = tid >> 1;
  const int shalf = tid & 1;
  const u16* Arow = A + (size_t)(m0 + srow) * K + shalf * 16;
  const u16* Brow = Bt + (size_t)(n0 + srow) * K + shalf * 16;
  char* asbase = (char*)As;
  char* bsbase = (char*)Bs;
  const u32 swz = (u32)((srow & 7) << 4);
  const u32 wb0 = (u32)(srow * 64 + shalf * 32);

  for (int kt = 0; kt < K; kt += 32) {
    __syncthreads();
    {
      u32x4 a0 = *(const u32x4*)(Arow + kt);
      u32x4 a1 = *(const u32x4*)(Arow + kt + 8);
      u32x4 b0 = *(const u32x4*)(Brow + kt);
      u32x4 b1 = *(const u32x4*)(Brow + kt + 8);
      *(u32x4*)(asbase + ((wb0 + 0) ^ swz)) = a0;
      *(u32x4*)(asbase + ((wb0 + 16) ^ swz)) = a1;
      *(u32x4*)(bsbase + ((wb0 + 0) ^ swz)) = b0;
      *(u32x4*)(bsbase + ((wb0 + 16) ^ swz)) = b1;
    }
    __syncthreads();
    u32x4 af[4], bfr[4];
#pragma unroll
    for (int fr = 0; fr < 4; fr++) {
      int row = wr + fr * 16 + c;
      af[fr] = *(const u32x4*)(asbase + ((u32)(row * 64 + g * 16) ^ ((u32)((row & 7) << 4))));
    }
#pragma unroll
    for (int fc = 0; fc < 4; fc++) {
      int row = wc + fc * 16 + c;
      bfr[fc] = *(const u32x4*)(bsbase + ((u32)(row * 64 + g * 16) ^ ((u32)((row & 7) << 4))));
    }
#pragma unroll
    for (int fr = 0; fr < 4; fr++)
#pragma unroll
      for (int fc = 0; fc < 4; fc++) mfma_b16(acc[fr][fc], af[fr], bfr[fc]);
  }
  mfma_fence();
#pragma unroll
  for (int fc = 0; fc < 4; fc++) {
    int gcol = n0 + wc + fc * 16 + c;
    float bvv = bias[gcol];
#pragma unroll
    for (int fr = 0; fr < 4; fr++) {
#pragma unroll
      for (int r = 0; r < 4; r++) {
        int grow = m0 + wr + fr * 16 + 4 * g + r;
        float v = acc[fr][fc][r] + bvv;
        if (MODE == 0) {
          int sel = gcol >> 9, c9 = gcol & 511;
          if (sel == 0) v *= QSCALE;
          int hh = c9 >> 6, dd = c9 & 63;
          int bb = grow >> 11, nn = grow & 2047;
          size_t off2 = ((size_t)(bb * 8 + hh) * 2048 + nn) * 64 + dd;
          u16* dst = sel == 0 ? outQ : (sel == 1 ? outK : outV);
          dst[off2] = f2bf(v);
        } else {
          outF[(size_t)grow * N + gcol] = v;
        }
      }
    }
  }
}

// ---------------------------------------------------------------------------
// transpose V: [BH][N][64] -> [BH][64][N] (bf16)
// ---------------------------------------------------------------------------
__global__ __launch_bounds__(256) void transpose_v(const u16* __restrict__ Vb,
                                                   u16* __restrict__ Vt) {
  __shared__ __align__(16) u16 T[64 * 72];
  const int nt = blockIdx.x, bh = blockIdx.y;
  const int tid = threadIdx.x;
  const int rr = tid >> 2, q = tid & 3;
  {
    const u16* src = Vb + ((size_t)bh * 2048 + nt * 64 + rr) * 64 + q * 16;
    u32x4 a = *(const u32x4*)src;
    u32x4 b = *(const u32x4*)(src + 8);
    *(u32x4*)(&T[rr * 72 + q * 16]) = a;
    *(u32x4*)(&T[rr * 72 + q * 16 + 8]) = b;
  }
  __syncthreads();
  {
    union { u16 s[16]; u32x4 v[2]; } ou;
#pragma unroll
    for (int e = 0; e < 16; e++) ou.s[e] = T[(q * 16 + e) * 72 + rr];
    u16* dst = Vt + ((size_t)bh * 64 + rr) * 2048 + nt * 64 + q * 16;
    *(u32x4*)dst = ou.v[0];
    *(u32x4*)(dst + 8) = ou.v[1];
  }
}

// ---------------------------------------------------------------------------
// flash attention, split-KV 2-way. Swapped-QK^T, QBLK=64, KVBLK=64, 16 tiles
// per block. Writes raw partials: o (f32, unscaled), (m, ssum) per row.
// Sparse bias direct from global with bucket jump table (tlo) for split 1.
// Grid: 2048 flat = qt(32) x split(2) x bh(32, XCD-grouped low bits).
// ---------------------------------------------------------------------------
__global__ __launch_bounds__(256) void attn_kernel(const u16* __restrict__ Qb,
                                                   const u16* __restrict__ Kb,
                                                   const u16* __restrict__ Vt,
                                                   const u32* __restrict__ tpw,
                                                   const u32* __restrict__ tstarts,
                                                   const u32* __restrict__ tlo,
                                                   float* __restrict__ opart,
                                                   float* __restrict__ mspart) {
  __shared__ __align__(16) u16 Ks[64 * 64];
  __shared__ __align__(16) u16 Vs[64 * 64];
  __shared__ __align__(16) u16 Ps[4][16 * 64];

  const int bid = blockIdx.x;
  const int bh = (bid & 7) * 4 + ((bid >> 3) & 3);
  const int split = (bid >> 5) & 1;
  const int qt = bid >> 6;
  const int b = bh >> 3;
  const int kv0 = split * 1024;
  const int tid = threadIdx.x, lane = tid & 63, w = tid >> 6;
  const int g = lane >> 4, c = lane & 15;
  const int qbase = qt * 64;
  const int rowl = w * 16 + c;

  // Q fragments (Q pre-scaled by 0.125*LOG2E at projection)
  const u16* qptr = Qb + ((size_t)bh * 2048 + qbase + rowl) * 64 + g * 8;
  u32x4 aq0 = *(const u32x4*)qptr;
  u32x4 aq1 = *(const u32x4*)(qptr + 32);

  // sparse-bias list: direct global reads, one-ahead prefetch
  const size_t rowgi = (size_t)b * 2048 + qbase + rowl;
  const u32* tpwrow = tpw + rowgi * 32;
  u32 stw = tstarts[rowgi];
  int p = (int)((stw >> (8 * g)) & 255u);
  const int pend = (g == 3) ? 32 : (int)((stw >> (8 * g + 8)) & 255u);
  if (split) p += (int)((tlo[rowgi] >> (8 * g)) & 255u);
  u32 nextE = (p < pend) ? tpwrow[p] : 0xFFFF0000u;  // j=65535 sentinel

  float m = -1e30f, ssum = 0.f;
  f32x4 o[4];
#pragma unroll
  for (int db = 0; db < 4; db++) o[db] = f32x4{0.f, 0.f, 0.f, 0.f};

  const int sr = tid >> 2, sq = tid & 3;
  const u16* ksrc = Kb + ((size_t)bh * 2048 + kv0 + sr) * 64 + sq * 16;
  const u16* vsrc = Vt + ((size_t)bh * 64 + sr) * 2048 + kv0 + sq * 16;
  char* ksb = (char*)Ks;
  char* vsb = (char*)Vs;
  char* pwb = (char*)&Ps[w][0];
  const u32 sswz = (u32)((sr & 7) << 4);
  const u32 sb0 = (u32)(sr * 128 + sq * 32);

  // hoisted LDS frag offsets
  u32 koff[4][2], poff2[2], pwoff[4];
#pragma unroll
  for (int cb = 0; cb < 4; cb++) {
    int row = cb * 16 + c;
    u32 sz = (u32)((row & 7) << 4);
    koff[cb][0] = ((u32)(row * 128 + g * 16)) ^ sz;
    koff[cb][1] = ((u32)(row * 128 + g * 16 + 64)) ^ sz;
  }
  {
    u32 sz = (u32)((c & 7) << 4);
#pragma unroll
    for (int mm = 0; mm < 2; mm++) poff2[mm] = ((u32)(c * 128 + mm * 64 + g * 16)) ^ sz;
#pragma unroll
    for (int cb = 0; cb < 4; cb++) pwoff[cb] = ((u32)(c * 128 + cb * 32 + g * 8)) ^ sz;
  }

  // prologue: load tile 0 into regs
  u32x4 rk0 = *(const u32x4*)ksrc;
  u32x4 rk1 = *(const u32x4*)(ksrc + 8);
  u32x4 rv0 = *(const u32x4*)vsrc;
  u32x4 rv1 = *(const u32x4*)(vsrc + 8);

  for (int t = 0; t < 16; ++t) {
    const int jt = kv0 + t * 64;  // absolute kv base of this tile
    __syncthreads();              // previous tile's readers done
    *(u32x4*)(ksb + ((sb0 + 0) ^ sswz)) = rk0;
    *(u32x4*)(ksb + ((sb0 + 16) ^ sswz)) = rk1;
    *(u32x4*)(vsb + ((sb0 + 0) ^ sswz)) = rv0;
    *(u32x4*)(vsb + ((sb0 + 16) ^ sswz)) = rv1;
    __syncthreads();  // tile t staged

    // issue next-tile loads now; latency hides under this tile's compute
    {
      int rel2 = t < 15 ? (t + 1) * 64 : 960;
      const u16* kp = ksrc + (size_t)rel2 * 64;
      const u16* vp = vsrc + rel2;
      rk0 = *(const u32x4*)kp;
      rk1 = *(const u32x4*)(kp + 8);
      rv0 = *(const u32x4*)vp;
      rv1 = *(const u32x4*)(vp + 8);
    }

    // S^T = K Q^T: lane holds S[kv=jt+16cb+4g+r][q=rowl]
    __builtin_amdgcn_s_setprio(1);
    f32x4 s[4];
#pragma unroll
    for (int cb = 0; cb < 4; cb++) {
      u32x4 bk0 = *(const u32x4*)(ksb + koff[cb][0]);
      u32x4 bk1 = *(const u32x4*)(ksb + koff[cb][1]);
      f32x4 tacc = f32x4{0.f, 0.f, 0.f, 0.f};
      mfma_b16(tacc, bk0, aq0);
      mfma_b16(tacc, bk1, aq1);
      s[cb] = tacc;
    }
    __builtin_amdgcn_s_setprio(0);
    mfma_fence();

    // sparse bias (this lane's g-bucket only), from global with prefetch
    const int jtend = jt + 64;
    while ((int)(nextE >> 16) < jtend) {
      float wv = __builtin_bit_cast(float, nextE << 16);
      int rel = (int)(nextE >> 16) - jt - 4 * g;
#pragma unroll
      for (int cb = 0; cb < 4; cb++)
#pragma unroll
        for (int r = 0; r < 4; r++) s[cb][r] += (rel == cb * 16 + r) ? wv : 0.f;
      p++;
      nextE = (p < pend) ? tpwrow[p] : 0xFFFF0000u;
    }

    // online softmax (exp2 domain), defer-max THR=8
    float tm = fmaxf(fmaxf(fmaxf(s[0][0], s[0][1]), fmaxf(s[0][2], s[0][3])),
                     fmaxf(fmaxf(s[1][0], s[1][1]), fmaxf(s[1][2], s[1][3])));
    tm = fmaxf(tm, fmaxf(fmaxf(fmaxf(s[2][0], s[2][1]), fmaxf(s[2][2], s[2][3])),
                         fmaxf(fmaxf(s[3][0], s[3][1]), fmaxf(s[3][2], s[3][3]))));
    tm = fmaxf(tm, __shfl_xor(tm, 16, 64));
    tm = fmaxf(tm, __shfl_xor(tm, 32, 64));
    if (!__all(tm - m <= 8.f)) {
      float mn = fmaxf(m, tm);
      float f = exp2v(m - mn);
      m = mn;
      ssum *= f;
#pragma unroll
      for (int db = 0; db < 4; db++) o[db] *= f;
    }
    float lsum = 0.f;
#pragma unroll
    for (int cb = 0; cb < 4; cb++) {
      float e0 = exp2v(s[cb][0] - m);
      float e1 = exp2v(s[cb][1] - m);
      float e2 = exp2v(s[cb][2] - m);
      float e3 = exp2v(s[cb][3] - m);
      lsum += (e0 + e1) + (e2 + e3);
      u32x2 pk;
      pk[0] = cvtpk(e0, e1);
      pk[1] = cvtpk(e2, e3);
      *(u32x2*)(pwb + pwoff[cb]) = pk;
    }
    ssum += lsum;

    // O^T += V^T P : o[db] cols q=c, rows d=db*16+4g+r
    u32x4 pf0 = *(const u32x4*)(pwb + poff2[0]);
    u32x4 pf1 = *(const u32x4*)(pwb + poff2[1]);
    __builtin_amdgcn_s_setprio(1);
#pragma unroll
    for (int db = 0; db < 4; db++) {
      u32x4 bv0 = *(const u32x4*)(vsb + koff[db][0]);
      u32x4 bv1 = *(const u32x4*)(vsb + koff[db][1]);
      mfma_b16(o[db], bv0, pf0);
      mfma_b16(o[db], bv1, pf1);
    }
    __builtin_amdgcn_s_setprio(0);
    // no fence: o[] not VALU-read until next tile's softmax at earliest
  }
  mfma_fence();

  ssum += __shfl_xor(ssum, 16, 64);
  ssum += __shfl_xor(ssum, 32, 64);
  // write partials: o unscaled + (m, ssum)
  const size_t pbase = ((size_t)split * 32 + bh) * 2048 + qbase + rowl;
  float* ob = opart + pbase * 64 + 4 * g;
#pragma unroll
  for (int db = 0; db < 4; db++) *(f32x4*)(ob + db * 16) = o[db];
  if (g == 0) {
    f32x2 msv;
    msv[0] = m;
    msv[1] = ssum;
    *(f32x2*)(mspart + pbase * 2) = msv;
  }
}

// ---------------------------------------------------------------------------
// merge split-KV partials -> attnout bf16 [B*N][512]. 4096 blocks x 256 thr,
// one f32x4 column-chunk per thread.
// ---------------------------------------------------------------------------
__global__ __launch_bounds__(256) void merge_kernel(const float* __restrict__ opart,
                                                    const float* __restrict__ mspart,
                                                    u16* __restrict__ attnout) {
  const int idx = blockIdx.x * 256 + threadIdx.x;  // 0..1048575
  const int row = idx >> 7;                        // 0..8191 (b*2048+n)
  const int c4 = (idx & 127) * 4;                  // col in [0,512)
  const int b = row >> 11, n = row & 2047;
  const int h = c4 >> 6, d = c4 & 63;
  const size_t base0 = ((size_t)(b * 8 + h)) * 2048 + n;
  const size_t base1 = base0 + 32 * 2048;
  f32x4 o0 = *(const f32x4*)(opart + base0 * 64 + d);
  f32x4 o1 = *(const f32x4*)(opart + base1 * 64 + d);
  f32x2 ms0 = *(const f32x2*)(mspart + base0 * 2);
  f32x2 ms1 = *(const f32x2*)(mspart + base1 * 2);
  float M = fmaxf(ms0[0], ms1[0]);
  float sc0 = exp2v(ms0[0] - M);
  float sc1 = exp2v(ms1[0] - M);
  float inv = 1.f / (ms0[1] * sc0 + ms1[1] * sc1);
  sc0 *= inv;
  sc1 *= inv;
  u32x2 st;
  st[0] = cvtpk(o0[0] * sc0 + o1[0] * sc1, o0[1] * sc0 + o1[1] * sc1);
  st[1] = cvtpk(o0[2] * sc0 + o1[2] * sc1, o0[3] * sc0 + o1[3] * sc1);
  *(u32x2*)(attnout + (size_t)row * 512 + c4) = st;
}

// ---------------------------------------------------------------------------
extern "C" void kernel_launch(void* const* d_in, const int* in_sizes, int n_in,
                              void* d_out, int out_size, void* d_ws, size_t ws_size,
                              hipStream_t stream) {
  (void)in_sizes; (void)n_in; (void)out_size; (void)ws_size;
  const float* x = (const float*)d_in[0];
  const float* sim = (const float*)d_in[1];
  const float* Wq = (const float*)d_in[2];
  const float* bq = (const float*)d_in[3];
  const float* Wk = (const float*)d_in[4];
  const float* bk = (const float*)d_in[5];
  const float* Wv = (const float*)d_in[6];
  const float* bv = (const float*)d_in[7];
  const float* Wo = (const float*)d_in[8];
  const float* bo = (const float*)d_in[9];
  const float* tau = (const float*)d_in[10];
  float* out = (float*)d_out;

  char* ws = (char*)d_ws;
  size_t off = 0;
  auto alloc = [&](size_t bytes) {
    void* p = ws + off;
    off += (bytes + 255) & ~(size_t)255;
    return p;
  };
  u16* xb = (u16*)alloc((size_t)8192 * 256 * 2);
  u16* WqkvT = (u16*)alloc((size_t)1536 * 256 * 2);
  u16* WoT = (u16*)alloc((size_t)512 * 512 * 2);
  float* biasQKV = (float*)alloc((size_t)1536 * 4);
  u16* Qb = (u16*)alloc((size_t)32 * 2048 * 64 * 2);
  u16* Kb = (u16*)alloc((size_t)32 * 2048 * 64 * 2);
  u16* Vb = (u16*)alloc((size_t)32 * 2048 * 64 * 2);
  u16* Vt = (u16*)alloc((size_t)32 * 2048 * 64 * 2);
  u16* attnout = (u16*)alloc((size_t)8192 * 512 * 2);
  u32* tpw = (u32*)alloc((size_t)8192 * 32 * 4);
  u32* tstarts = (u32*)alloc((size_t)8192 * 4);
  u32* tlo = (u32*)alloc((size_t)8192 * 4);
  float* opart = (float*)alloc((size_t)2 * 32 * 2048 * 64 * 4);
  float* mspart = (float*)alloc((size_t)2 * 32 * 2048 * 2 * 4);

  prep_kernel<<<dim3(1185), dim3(256), 0, stream>>>(x, Wq, Wk, Wv, Wo, bq, bk, bv, xb, WqkvT,
                                                    WoT, biasQKV);
  topk_kernel<<<dim3(2048), dim3(256), 0, stream>>>(sim, tau, tpw, tstarts, tlo);
  gemm_nt<0><<<dim3(12, 64), dim3(256), 0, stream>>>(xb, WqkvT, biasQKV, Qb, Kb, Vb, nullptr,
                                                     8192, 1536, 256);
  transpose_v<<<dim3(32, 32), dim3(256), 0, stream>>>(Vb, Vt);
  attn_kernel<<<dim3(2048), dim3(256), 0, stream>>>(Qb, Kb, Vt, tpw, tstarts, tlo, opart,
                                                    mspart);
  merge_kernel<<<dim3(4096), dim3(256), 0, stream>>>(opart, mspart, attnout);
  gemm_nt<1><<<dim3(4, 64), dim3(256), 0, stream>>>(attnout, WoT, bo, nullptr, nullptr, nullptr,
                                                    out, 8192, 512, 512);
}